// Round 4
// baseline (44905.478 us; speedup 1.0000x reference)
//
#include <hip/hip_runtime.h>
#include <math.h>

// Problem constants
#define B 256
#define Hh 512
#define S 200
#define T 200
#define VOC 512
#define G3 1536
#define PAD 36

// fp64 helpers: inner-product math in double, tensor boundaries quantized fp32.
struct d4 { double x, y, z, w; };
__device__ __forceinline__ d4 tod4(const float4 a) {
    d4 r; r.x = a.x; r.y = a.y; r.z = a.z; r.w = a.w; return r;
}
__device__ __forceinline__ double dotd(const d4& a, const d4& b) {
    return a.x * b.x + a.y * b.y + a.z * b.z + a.w * b.w;
}
__device__ __forceinline__ double sigd(double x) { return 1.0 / (1.0 + exp(-x)); }

typedef double f64x4 __attribute__((ext_vector_type(4)));

__device__ __forceinline__ unsigned long long dbits(double v) {
    return (unsigned long long)__double_as_longlong(v);
}

// ---------------------------------------------------------------------------
// Self-calibration for v_mfma_f64_16x16x4f64 (round-3 proven, absmax 0.0):
// decodes A-operand lane map and per-register D-row map at runtime from two
// probe MFMAs with exact power-of-two inputs. B map and D-col are pinned by
// the round-2 hardware probe: B: n=lane&15, k=lane>>4; D col = lane&15.
// ---------------------------------------------------------------------------
__device__ __forceinline__ void calib(int lane, int& am, int& ak, int* rowd)
{
    f64x4 z = { 0.0, 0.0, 0.0, 0.0 };
    f64x4 va = __builtin_amdgcn_mfma_f64_16x16x4f64(
        (double)(1ULL << lane), 1.0, z, 0, 0, 0);
    const unsigned long long MM = 0xFFFFFFFFFFFFFULL;
    const unsigned long long M0 = (1ULL << 36) | (1ULL << 20) | (1ULL << 4);
    const int fam0 = __all(
        ((dbits(va[0]) & MM) == M0) && ((dbits(va[1]) & MM) == M0) &&
        ((dbits(va[2]) & MM) == M0) && ((dbits(va[3]) & MM) == M0));
    am = fam0 ? (lane & 15) : (lane >> 2);
    ak = fam0 ? (lane >> 4) : (lane & 3);
    f64x4 vr = __builtin_amdgcn_mfma_f64_16x16x4f64(
        (double)(1ULL << am), 1.0, z, 0, 0, 0);
#pragma unroll
    for (int d = 0; d < 4; ++d)
        rowd[d] = (int)((dbits(vr[d]) >> 52) & 0x7ff) - 1025;
}

// ---------------------------------------------------------------------------
// Table-precompute GEMM (proven): C[m,j] = sum_k A[m,k]*W[j*ldw+woff+k]+bias[j]
// ---------------------------------------------------------------------------
__global__ __launch_bounds__(256) void gemm_at(
    const float* __restrict__ A,
    const float* __restrict__ W, int ldw, int woff,
    const float* __restrict__ bias,
    float* __restrict__ C, int ldc)
{
    __shared__ float As[32][PAD];
    __shared__ float Ws[32][PAD];
    const int tid = threadIdx.x;
    const int tx = tid & 15, ty = tid >> 4;
    const int j0 = blockIdx.x * 32, m0 = blockIdx.y * 32;
    const int lr = tid >> 3, lc = (tid & 7) * 4;

    double acc00 = 0.0, acc01 = 0.0, acc10 = 0.0, acc11 = 0.0;

    for (int k0 = 0; k0 < 512; k0 += 32) {
        float4 av = *(const float4*)(A + (size_t)(m0 + lr) * 512 + k0 + lc);
        float4 wv = *(const float4*)(W + (size_t)(j0 + lr) * ldw + woff + k0 + lc);
        __syncthreads();
        *(float4*)&As[lr][lc] = av;
        *(float4*)&Ws[lr][lc] = wv;
        __syncthreads();
#pragma unroll
        for (int kk = 0; kk < 32; kk += 4) {
            d4 a0 = tod4(*(const float4*)&As[ty][kk]);
            d4 a1 = tod4(*(const float4*)&As[ty + 16][kk]);
            d4 b0 = tod4(*(const float4*)&Ws[tx][kk]);
            d4 b1 = tod4(*(const float4*)&Ws[tx + 16][kk]);
            acc00 += dotd(a0, b0);
            acc01 += dotd(a0, b1);
            acc10 += dotd(a1, b0);
            acc11 += dotd(a1, b1);
        }
    }
    const int ms[2] = { m0 + ty, m0 + ty + 16 };
    const int js[2] = { j0 + tx, j0 + tx + 16 };
    double accs[2][2] = { { acc00, acc01 }, { acc10, acc11 } };
#pragma unroll
    for (int mi = 0; mi < 2; ++mi)
#pragma unroll
        for (int ji = 0; ji < 2; ++ji) {
            int m = ms[mi], j = js[ji];
            C[(size_t)m * ldc + j] = (float)(accs[mi][ji] + (double)bias[j]);
        }
}

// ---------------------------------------------------------------------------
// Fused encoder GRU step: grid (32 j-tiles, 16 b-tiles) x 64 thr (1 wave).
// Per (16b x 16j) tile: 3 MFMA chains (r,z,n gates of h@Whh^T), k-ascending
// per output (bitwise-identical sums to round-3's proven gemm64 chains),
// then the exact enc_combine epilogue in-register. Block-uniform early-out.
// ---------------------------------------------------------------------------
__global__ __launch_bounds__(64) void enc_mfma(
    const float* __restrict__ h_in, float* __restrict__ h_out,
    const float* __restrict__ gi_tab, const int* __restrict__ iseq,
    const int* __restrict__ ilen, const float* __restrict__ Whh,
    const float* __restrict__ bhh, int s, float* __restrict__ enc_out)
{
    const int lane = threadIdx.x;
    const int j0 = blockIdx.x * 16, b0 = blockIdx.y * 16;

    int ml = 0;
    for (int i = 0; i < 16; ++i) ml = max(ml, ilen[b0 + i]);
    if (s >= ml) {   // whole tile past lengths: copy h, zero enc_out
        for (int i = lane; i < 256; i += 64) {
            int bq = b0 + (i >> 4), jq = j0 + (i & 15);
            h_out[(size_t)bq * 512 + jq] = h_in[(size_t)bq * 512 + jq];
            enc_out[((size_t)s * B + bq) * 512 + jq] = 0.f;
        }
        return;
    }

    __shared__ float Ws[64][68];   // rows 0-47: Whh gates r,z,n; 48-63: h rows
    const int lr = lane & 15, gk = lane >> 4;
    int am, ak, rowd[4];
    calib(lane, am, ak, rowd);

    auto rowptr = [&](int r) -> const float* {
        if (r < 48) return Whh + ((size_t)((r >> 4) * 512 + j0 + (r & 15))) * 512;
        return h_in + (size_t)(b0 + r - 48) * 512;
    };

    float4 wreg[16];
#pragma unroll
    for (int i = 0; i < 16; ++i) {
        int x4 = i * 64 + lane, row = x4 >> 4, c4 = (x4 & 15) * 4;
        wreg[i] = *(const float4*)(rowptr(row) + c4);
    }
#pragma unroll
    for (int i = 0; i < 16; ++i) {
        int x4 = i * 64 + lane, row = x4 >> 4, c4 = (x4 & 15) * 4;
        *(float4*)&Ws[row][c4] = wreg[i];
    }
    __syncthreads();

    f64x4 c0 = {0,0,0,0}, c1 = {0,0,0,0}, c2 = {0,0,0,0};
    for (int k0 = 0; k0 < 512; k0 += 64) {
        const bool more = (k0 + 64) < 512;
        if (more) {
#pragma unroll
            for (int i = 0; i < 16; ++i) {
                int x4 = i * 64 + lane, row = x4 >> 4, c4 = (x4 & 15) * 4;
                wreg[i] = *(const float4*)(rowptr(row) + k0 + 64 + c4);
            }
        }
#pragma unroll
        for (int kk = 0; kk < 16; ++kk) {
            double a  = (double)Ws[48 + am][kk * 4 + ak];
            double br = (double)Ws[lr][kk * 4 + gk];
            double bz = (double)Ws[16 + lr][kk * 4 + gk];
            double bn = (double)Ws[32 + lr][kk * 4 + gk];
            c0 = __builtin_amdgcn_mfma_f64_16x16x4f64(a, br, c0, 0, 0, 0);
            c1 = __builtin_amdgcn_mfma_f64_16x16x4f64(a, bz, c1, 0, 0, 0);
            c2 = __builtin_amdgcn_mfma_f64_16x16x4f64(a, bn, c2, 0, 0, 0);
        }
        __syncthreads();
        if (more) {
#pragma unroll
            for (int i = 0; i < 16; ++i) {
                int x4 = i * 64 + lane, row = x4 >> 4, c4 = (x4 & 15) * 4;
                *(float4*)&Ws[row][c4] = wreg[i];
            }
            __syncthreads();
        }
    }

    // Epilogue: exact enc_combine arithmetic, per hardware-reported row.
    const int j = j0 + lr;
#pragma unroll
    for (int d = 0; d < 4; ++d) {
        const int b = b0 + rowd[d];
        float hold = h_in[(size_t)b * 512 + j];
        float hnew = hold;
        if (s < ilen[b]) {
            int tok = iseq[s * B + b];
            const float* gi = gi_tab + (size_t)tok * G3;
            double r = sigd((double)gi[j] + c0[d] + (double)bhh[j]);
            double z = sigd((double)gi[512 + j] + c1[d] + (double)bhh[512 + j]);
            double n = tanh((double)gi[1024 + j] + r * (c2[d] + (double)bhh[1024 + j]));
            hnew = (float)((1.0 - z) * n + z * (double)hold);
            enc_out[((size_t)s * B + b) * 512 + j] = hnew;
        } else {
            enc_out[((size_t)s * B + b) * 512 + j] = 0.f;
        }
        h_out[(size_t)b * 512 + j] = hnew;
    }
}

// ---------------------------------------------------------------------------
// K1 (dec_att), grid 640 x 256 thr:
//  blocks [0,256):   per-b: ah = relu(h@attW^T+b) in-LDS (quad-per-row, same
//                    pattern as proven x-matvec), then attention + ctx + x.
//  blocks [256,512): softmax/argmax/nll of logits(h_{t-1}) -> dist[t-2].
//  blocks [512,640): MFMA logits GEMM lgbA = h_t @ out_W^T + out_b.
// Logits double-buffered across launches (lgbA write / lgbB read).
// ---------------------------------------------------------------------------
union K1sm {
    struct {
        float scx[4][512];
        float ctxl[512];
        float hl[512];
        float ah_l[512];
        double sml[8];
    } a;
    struct {
        float red_f[256];
        double red_d[256];
        int red_i[256];
    } s;
    struct {
        float As[16][68];
        float Ws[64][68];
    } g;
};

__global__ __launch_bounds__(256) void dec_att(
    const float* __restrict__ enc_out, const float* __restrict__ h,
    const float* __restrict__ att_W, const float* __restrict__ att_b,
    const float* __restrict__ out_W, const float* __restrict__ out_b,
    const float* __restrict__ mlp_W, const float* __restrict__ mlp_tab,
    const int* __restrict__ input_len, const int* __restrict__ target_seq,
    float* __restrict__ lgbA, const float* __restrict__ lgbB, int t,
    float* __restrict__ xbuf, float* __restrict__ nll,
    float* __restrict__ inference)
{
    __shared__ K1sm sm;
    const int bid = blockIdx.x, tid = threadIdx.x;

    if (bid < B) {
        if (t >= T) return;
        const int b = bid;
        // stage h row b
        for (int i = tid; i < 128; i += 256)
            *(float4*)&sm.a.hl[i * 4] =
                *(const float4*)(h + (size_t)b * 512 + i * 4);
        __syncthreads();
        // ah = relu(h@attW^T + att_b), fp32 quantized (as proven proj)
        {
            const int q = tid & 3, rbase = tid >> 2;
#pragma unroll
            for (int pass = 0; pass < 8; ++pass) {
                const int jr = pass * 64 + rbase;
                const float* wr = att_W + (size_t)jr * 512;
                double a = 0.0;
                for (int k = q * 4; k < 512; k += 16)
                    a += dotd(tod4(*(const float4*)&sm.a.hl[k]),
                              tod4(*(const float4*)(wr + k)));
                a += __shfl_xor(a, 1, 64);
                a += __shfl_xor(a, 2, 64);
                if (q == 0) {
                    double v = a + (double)att_b[jr];
                    if (v < 0.0) v = 0.0;
                    sm.a.ah_l[jr] = (float)v;
                }
            }
        }
        __syncthreads();

        const int wave = tid >> 6, lane = tid & 63;
        const int len = input_len[b];
        d4 aa1 = tod4(*(const float4*)&sm.a.ah_l[lane * 4]);
        d4 aa2 = tod4(*(const float4*)&sm.a.ah_l[256 + lane * 4]);
        double m = -INFINITY, l = 0.0;
        d4 c1 = {0,0,0,0}, c2 = {0,0,0,0};
        for (int s = wave; s < len; s += 4) {
            const float* row = enc_out + ((size_t)s * B + b) * 512;
            d4 e1 = tod4(*(const float4*)(row + lane * 4));
            d4 e2 = tod4(*(const float4*)(row + 256 + lane * 4));
            double p = dotd(e1, aa1) + dotd(e2, aa2);
#pragma unroll
            for (int off = 32; off >= 1; off >>= 1) p += __shfl_xor(p, off, 64);
            double mn = fmax(m, p);
            double sc = (m == mn) ? 1.0 : exp(m - mn);   // exp(0)==1 exactly
            double w = exp(p - mn);
            l = l * sc + w;
            c1.x = c1.x * sc + w * e1.x; c1.y = c1.y * sc + w * e1.y;
            c1.z = c1.z * sc + w * e1.z; c1.w = c1.w * sc + w * e1.w;
            c2.x = c2.x * sc + w * e2.x; c2.y = c2.y * sc + w * e2.y;
            c2.z = c2.z * sc + w * e2.z; c2.w = c2.w * sc + w * e2.w;
            m = mn;
        }
        if (lane == 0) { sm.a.sml[wave] = m; sm.a.sml[4 + wave] = l; }
        *(float4*)&sm.a.scx[wave][lane * 4] =
            make_float4((float)c1.x, (float)c1.y, (float)c1.z, (float)c1.w);
        *(float4*)&sm.a.scx[wave][256 + lane * 4] =
            make_float4((float)c2.x, (float)c2.y, (float)c2.z, (float)c2.w);
        __syncthreads();
        double M = fmax(fmax(sm.a.sml[0], sm.a.sml[1]),
                        fmax(sm.a.sml[2], sm.a.sml[3]));
        if (len < S) M = fmax(M, 0.0);   // zero rows participate in softmax
        double w0 = exp(sm.a.sml[0] - M), w1x = exp(sm.a.sml[1] - M);
        double w2x = exp(sm.a.sml[2] - M), w3 = exp(sm.a.sml[3] - M);
        double L = sm.a.sml[4] * w0 + sm.a.sml[5] * w1x + sm.a.sml[6] * w2x
                 + sm.a.sml[7] * w3 + (double)(S - len) * exp(0.0 - M);
        for (int jj = tid; jj < 512; jj += 256) {
            double v = (double)sm.a.scx[0][jj] * w0 + (double)sm.a.scx[1][jj] * w1x
                     + (double)sm.a.scx[2][jj] * w2x + (double)sm.a.scx[3][jj] * w3;
            sm.a.ctxl[jj] = (float)(v / L);   // fp32 quantization boundary
        }
        __syncthreads();

        // x = tanh(mlp_tab[tok] + ctx @ mlpW2^T): quad-per-row (proven)
        const int tok = (t == 0) ? 1 : target_seq[(t - 1) * B + b];
        const int q = tid & 3;
        const int rbase = tid >> 2;
#pragma unroll
        for (int pass = 0; pass < 8; ++pass) {
            const int jr = pass * 64 + rbase;
            const float* wr = mlp_W + (size_t)jr * 1024 + 512;
            double a = 0.0;
            for (int k = q * 4; k < 512; k += 16) {
                a += dotd(tod4(*(const float4*)&sm.a.ctxl[k]),
                          tod4(*(const float4*)(wr + k)));
            }
            a += __shfl_xor(a, 1, 64);
            a += __shfl_xor(a, 2, 64);
            if (q == 0)
                xbuf[(size_t)b * 512 + jr] =
                    (float)tanh((double)mlp_tab[(size_t)tok * 512 + jr] + a);
        }
    } else if (bid < 2 * B) {
        if (t < 2) return;
        const int sb = bid - B;
        const int dt = t - 2;
        const float* lg = lgbB + (size_t)sb * 512;
        const float l0 = lg[tid], l1 = lg[256 + tid];
        sm.s.red_f[tid] = fmaxf(l0, l1);
        __syncthreads();
        for (int off = 128; off > 0; off >>= 1) {
            if (tid < off)
                sm.s.red_f[tid] = fmaxf(sm.s.red_f[tid], sm.s.red_f[tid + off]);
            __syncthreads();
        }
        const double mx = (double)sm.s.red_f[0];
        __syncthreads();
        const double e0 = exp((double)l0 - mx), e1 = exp((double)l1 - mx);
        sm.s.red_d[tid] = e0 + e1;
        __syncthreads();
        for (int off = 128; off > 0; off >>= 1) {
            if (tid < off) sm.s.red_d[tid] += sm.s.red_d[tid + off];
            __syncthreads();
        }
        const double Z = sm.s.red_d[0];
        __syncthreads();
        const float p0 = (float)(e0 / Z), p1 = (float)(e1 / Z);
        float v; int idx;
        if (p0 >= p1) { v = p0; idx = tid; } else { v = p1; idx = 256 + tid; }
        sm.s.red_f[tid] = v; sm.s.red_i[tid] = idx;
        __syncthreads();
        for (int off = 128; off > 0; off >>= 1) {
            if (tid < off) {
                float ov = sm.s.red_f[tid + off]; int oi = sm.s.red_i[tid + off];
                if (ov > sm.s.red_f[tid] ||
                    (ov == sm.s.red_f[tid] && oi < sm.s.red_i[tid])) {
                    sm.s.red_f[tid] = ov; sm.s.red_i[tid] = oi;
                }
            }
            __syncthreads();
        }
        if (tid == 0) {
            int tg = target_seq[dt * B + sb];
            float pt = (float)(exp((double)lg[tg] - mx) / Z);
            pt = fmaxf(pt, 1e-10f);
            nll[dt * B + sb] = (float)(-log((double)pt));
            inference[dt * B + sb] = (float)sm.s.red_i[0];
        }
    } else {
        if (t < 1 || t > T) return;
        const int g = bid - 2 * B;              // 0..127
        const int n0 = (g & 7) * 64, m0 = (g >> 3) * 16;
        const int lane = tid & 63, wv = tid >> 6;
        const int lr = lane & 15, gk = lane >> 4;
        int am, ak, rowd[4];
        calib(lane, am, ak, rowd);

        const int arow = tid >> 4, ac4 = (tid & 15) * 4;
        float4 areg = *(const float4*)(h + (size_t)(m0 + arow) * 512 + ac4);
        float4 wreg[4];
#pragma unroll
        for (int i = 0; i < 4; ++i) {
            int x4 = i * 256 + tid, row = x4 >> 4, c4 = (x4 & 15) * 4;
            wreg[i] = *(const float4*)(out_W + (size_t)(n0 + row) * 512 + c4);
        }
        *(float4*)&sm.g.As[arow][ac4] = areg;
#pragma unroll
        for (int i = 0; i < 4; ++i) {
            int x4 = i * 256 + tid, row = x4 >> 4, c4 = (x4 & 15) * 4;
            *(float4*)&sm.g.Ws[row][c4] = wreg[i];
        }
        __syncthreads();

        f64x4 c = {0,0,0,0};
        for (int k0 = 0; k0 < 512; k0 += 64) {
            const bool more = (k0 + 64) < 512;
            if (more) {
                areg = *(const float4*)(h + (size_t)(m0 + arow) * 512
                                        + k0 + 64 + ac4);
#pragma unroll
                for (int i = 0; i < 4; ++i) {
                    int x4 = i * 256 + tid, row = x4 >> 4, c4 = (x4 & 15) * 4;
                    wreg[i] = *(const float4*)(out_W + (size_t)(n0 + row) * 512
                                               + k0 + 64 + c4);
                }
            }
#pragma unroll
            for (int kk = 0; kk < 16; ++kk) {
                double a  = (double)sm.g.As[am][kk * 4 + ak];
                double bb = (double)sm.g.Ws[wv * 16 + lr][kk * 4 + gk];
                c = __builtin_amdgcn_mfma_f64_16x16x4f64(a, bb, c, 0, 0, 0);
            }
            __syncthreads();
            if (more) {
                *(float4*)&sm.g.As[arow][ac4] = areg;
#pragma unroll
                for (int i = 0; i < 4; ++i) {
                    int x4 = i * 256 + tid, row = x4 >> 4, c4 = (x4 & 15) * 4;
                    *(float4*)&sm.g.Ws[row][c4] = wreg[i];
                }
                __syncthreads();
            }
        }
        const int ng = n0 + wv * 16 + lr;
#pragma unroll
        for (int d = 0; d < 4; ++d)
            lgbA[(size_t)(m0 + rowd[d]) * 512 + ng] =
                (float)(c[d] + (double)out_b[ng]);
    }
}

// ---------------------------------------------------------------------------
// K2 (dec_gru2): fused decoder GRU. Grid (32 j-tiles, 16 b-tiles) x 128 thr.
// wave0: 3 chains x@Wih^T; wave1: 3 chains h@Whh^T; LDS exchange; exact
// dec_combine epilogue. Chains k-ascending (bitwise = round-3 gemm64 sums).
// ---------------------------------------------------------------------------
__global__ __launch_bounds__(128) void dec_gru2(
    const float* __restrict__ x, const float* __restrict__ h_in,
    const float* __restrict__ Wih, const float* __restrict__ Whh,
    const float* __restrict__ bih, const float* __restrict__ bhh,
    float* __restrict__ h_out)
{
    __shared__ float Ws[128][68];   // 0-47 Wi gates; 48-95 Wh gates; 96-111 x; 112-127 h
    __shared__ double Lx[3][4][64];
    const int tid = threadIdx.x;
    const int lane = tid & 63, wv = tid >> 6;
    const int j0 = blockIdx.x * 16, b0 = blockIdx.y * 16;
    const int lr = lane & 15, gk = lane >> 4;
    int am, ak, rowd[4];
    calib(lane, am, ak, rowd);

    auto rowptr = [&](int r) -> const float* {
        if (r < 48)
            return Wih + ((size_t)((r >> 4) * 512 + j0 + (r & 15))) * 512;
        if (r < 96) {
            int rr = r - 48;
            return Whh + ((size_t)((rr >> 4) * 512 + j0 + (rr & 15))) * 512;
        }
        if (r < 112) return x + (size_t)(b0 + r - 96) * 512;
        return h_in + (size_t)(b0 + r - 112) * 512;
    };

    float4 wreg[16];
#pragma unroll
    for (int i = 0; i < 16; ++i) {
        int x4 = i * 128 + tid, row = x4 >> 4, c4 = (x4 & 15) * 4;
        wreg[i] = *(const float4*)(rowptr(row) + c4);
    }
#pragma unroll
    for (int i = 0; i < 16; ++i) {
        int x4 = i * 128 + tid, row = x4 >> 4, c4 = (x4 & 15) * 4;
        *(float4*)&Ws[row][c4] = wreg[i];
    }
    __syncthreads();

    const int ab = 96 + wv * 16;   // A rows: x (wave0) or h (wave1)
    const int bb = wv * 48;        // B rows: Wi (wave0) or Wh (wave1)
    f64x4 c0 = {0,0,0,0}, c1 = {0,0,0,0}, c2 = {0,0,0,0};

    for (int k0 = 0; k0 < 512; k0 += 64) {
        const bool more = (k0 + 64) < 512;
        if (more) {
#pragma unroll
            for (int i = 0; i < 16; ++i) {
                int x4 = i * 128 + tid, row = x4 >> 4, c4 = (x4 & 15) * 4;
                wreg[i] = *(const float4*)(rowptr(row) + k0 + 64 + c4);
            }
        }
#pragma unroll
        for (int kk = 0; kk < 16; ++kk) {
            double a  = (double)Ws[ab + am][kk * 4 + ak];
            double br = (double)Ws[bb + lr][kk * 4 + gk];
            double bz = (double)Ws[bb + 16 + lr][kk * 4 + gk];
            double bn = (double)Ws[bb + 32 + lr][kk * 4 + gk];
            c0 = __builtin_amdgcn_mfma_f64_16x16x4f64(a, br, c0, 0, 0, 0);
            c1 = __builtin_amdgcn_mfma_f64_16x16x4f64(a, bz, c1, 0, 0, 0);
            c2 = __builtin_amdgcn_mfma_f64_16x16x4f64(a, bn, c2, 0, 0, 0);
        }
        __syncthreads();
        if (more) {
#pragma unroll
            for (int i = 0; i < 16; ++i) {
                int x4 = i * 128 + tid, row = x4 >> 4, c4 = (x4 & 15) * 4;
                *(float4*)&Ws[row][c4] = wreg[i];
            }
            __syncthreads();
        }
    }

    if (wv == 1) {
#pragma unroll
        for (int d = 0; d < 4; ++d) {
            Lx[0][d][lane] = c0[d];
            Lx[1][d][lane] = c1[d];
            Lx[2][d][lane] = c2[d];
        }
    }
    __syncthreads();
    if (wv == 0) {
        const int j = j0 + lr;
#pragma unroll
        for (int d = 0; d < 4; ++d) {
            const int b = b0 + rowd[d];
            double air = c0[d], aiz = c1[d], ain = c2[d];
            double ahr = Lx[0][d][lane], ahz = Lx[1][d][lane],
                   ahn = Lx[2][d][lane];
            double r = sigd(air + (double)bih[j] + ahr + (double)bhh[j]);
            double z = sigd(aiz + (double)bih[512 + j] + ahz + (double)bhh[512 + j]);
            double n = tanh(ain + (double)bih[1024 + j]
                            + r * (ahn + (double)bhh[1024 + j]));
            float hold = h_in[(size_t)b * 512 + j];
            h_out[(size_t)b * 512 + j] = (float)((1.0 - z) * n + z * (double)hold);
        }
    }
}

// ---------------------------------------------------------------------------
// Final reduction (proven).
// ---------------------------------------------------------------------------
__global__ __launch_bounds__(256) void finalize_k(
    const float* __restrict__ nll, const float* __restrict__ inference,
    const int* __restrict__ target, float* __restrict__ out3)
{
    const int tid = threadIdx.x;
    int wrong = 0;
    double match = 0.0;
    const int b = tid;
    for (int t = 0; t < T; ++t) {
        float inf = inference[t * B + b];
        float tg = (float)target[t * B + b];
        bool ok = (inf == tg);
        match += ok ? 1.0 : 0.0;
        wrong |= !ok;
    }
    double lsum = 0.0;
    for (int i = tid; i < T * B; i += 256) lsum += (double)nll[i];

    __shared__ double sl[256], sm_[256], sa[256];
    sl[tid] = lsum; sm_[tid] = match; sa[tid] = wrong ? 0.0 : 1.0;
    __syncthreads();
    for (int off = 128; off > 0; off >>= 1) {
        if (tid < off) {
            sl[tid] += sl[tid + off];
            sm_[tid] += sm_[tid + off];
            sa[tid] += sa[tid + off];
        }
        __syncthreads();
    }
    if (tid == 0) {
        out3[0] = (float)(sl[0] / (double)(T * B));
        out3[1] = (float)(sa[0] / (double)B);
        out3[2] = (float)(sm_[0] / (double)(T * B));
    }
}

// ---------------------------------------------------------------------------
extern "C" void kernel_launch(void* const* d_in, const int* in_sizes, int n_in,
                              void* d_out, int out_size, void* d_ws, size_t ws_size,
                              hipStream_t stream)
{
    const int*   input_seq  = (const int*)d_in[0];
    const int*   input_len  = (const int*)d_in[1];
    const int*   target_seq = (const int*)d_in[2];
    const float* enc_embed  = (const float*)d_in[3];
    const float* enc_Wih    = (const float*)d_in[4];
    const float* enc_Whh    = (const float*)d_in[5];
    const float* enc_bih    = (const float*)d_in[6];
    const float* enc_bhh    = (const float*)d_in[7];
    const float* att_W      = (const float*)d_in[8];
    const float* att_b      = (const float*)d_in[9];
    const float* dec_embed  = (const float*)d_in[10];
    const float* dec_Wih    = (const float*)d_in[11];
    const float* dec_Whh    = (const float*)d_in[12];
    const float* dec_bih    = (const float*)d_in[13];
    const float* dec_bhh    = (const float*)d_in[14];
    const float* mlp_W      = (const float*)d_in[15];
    const float* mlp_b      = (const float*)d_in[16];
    const float* out_W      = (const float*)d_in[17];
    const float* out_b      = (const float*)d_in[18];

    float* out = (float*)d_out;   // [inference (T*B) | loss | acc | all_acc]

    // Workspace layout identical to round-0 (verified size-safe); the old
    // ahb slot is repurposed as the second logits buffer.
    float* gi_tab  = (float*)d_ws;                   // (V, 3H)
    float* mlp_tab = gi_tab + (size_t)VOC * G3;      // (V, H)
    float* h0      = mlp_tab + (size_t)VOC * Hh;     // (B, H)
    float* h1      = h0 + (size_t)B * Hh;
    float* lgb_odd = h1 + (size_t)B * Hh;            // (B, H)  [was ahb]
    float* xb      = lgb_odd + (size_t)B * Hh;
    float* lgb_evn = xb + (size_t)B * Hh;            // (B, H)  [was lgb]
    float* nllb    = lgb_evn + (size_t)B * Hh;       // (T, B)
    float* enc_out = nllb + (size_t)T * B;           // (S, B, H) ~100 MB

    hipMemsetAsync(h0, 0, (size_t)B * Hh * sizeof(float), stream);

    // Precompute tables:
    gemm_at<<<dim3(48, 16), 256, 0, stream>>>(
        enc_embed, enc_Wih, 512, 0, enc_bih, gi_tab, G3);
    gemm_at<<<dim3(16, 16), 256, 0, stream>>>(
        dec_embed, mlp_W, 1024, 0, mlp_b, mlp_tab, Hh);

    // Encoder scan (final h lands in h0: s=199 odd writes h0)
    for (int s = 0; s < S; ++s) {
        const float* hc = (s & 1) ? h1 : h0;
        float* hx = (s & 1) ? h0 : h1;
        enc_mfma<<<dim3(32, 16), 64, 0, stream>>>(
            hc, hx, gi_tab, input_seq, input_len, enc_Whh, enc_bhh, s, enc_out);
    }

    // Decoder: K1(t) for t=0..T+1, K2(t) for t=0..T-1.
    //  K1(t): attn+x from h_t (t<T); logits(h_t)->lgb[t&1] (1<=t<=T);
    //         softmax of lgb[(t-1)&1] -> dist[t-2] (t>=2).
    for (int t = 0; t <= T + 1; ++t) {
        const float* hc = (t & 1) ? h1 : h0;
        float* hx = (t & 1) ? h0 : h1;
        float* lgbA = (t & 1) ? lgb_odd : lgb_evn;
        const float* lgbB = (t & 1) ? lgb_evn : lgb_odd;
        dec_att<<<dim3(640), 256, 0, stream>>>(
            enc_out, hc, att_W, att_b, out_W, out_b, mlp_W, mlp_tab,
            input_len, target_seq, lgbA, lgbB, t, xb, nllb, out);
        if (t < T) {
            dec_gru2<<<dim3(32, 16), 128, 0, stream>>>(
                xb, hc, dec_Wih, dec_Whh, dec_bih, dec_bhh, hx);
        }
    }

    finalize_k<<<dim3(1), 256, 0, stream>>>(nllb, out, target_seq, out + (size_t)T * B);
}